// Round 13
// baseline (232.295 us; speedup 1.0000x reference)
//
#include <hip/hip_runtime.h>

// CustomConv2d: 3x3 conv, stride 1, pad 1. B=32, Cin=128, H=W=56, Cout=256.
// fp32 in/out (round-1 NaN proved it); per-wave dtype self-detection keeps
// robustness without a separate serialized detect dispatch.
//
// Implicit GEMM, internally bf16. M=cout(256), N=b*h*w(100352), K=cin*9(1152).
// Round-19: ladder: r9 (A+B LDS, 3-deep counted vmcnt, 4 waves x 128x64,
// 2 blocks/CU) 86.5us/29% beats every variant that removed work from its
// loop (lockstep 93, ordering 101, drain 109, barrier-free 125, no-LDS 141,
// fat-tile 272). r9's counters: all pipes <35%, ~2000cyc/half of stall with
// only 2 wave-streams/SIMD to fill it. This round keeps r9's structure and
// ledger EXACTLY and doubles the independent streams per SIMD:
//   - 8 waves (512 thr) x 64x64 wave tiles, same 256x128 block tile, same
//     3 x 24KB LDS (2 blocks/CU) -> 4 waves/SIMD (2 per block): when one
//     block's waves convoy at the gate, the other block's 2 waves + same
//     block's sibling fill the hole
//   - per-wave ledger rescaled: 3 stage loads/body (2 A + 1 B chunks),
//     gates vmcnt(3) steady / vmcnt(0) at h=34 (was 6 loads, vmcnt(6))
//   - +33% fragment reads (64 vs 48 KB/half/block) - LDS was at ~30% BW
//   - acc[4][4]=64 AGPR + ~100 VGPR: no spill at 4 waves/SIMD (512/wave)
//   - dtype sniff moved AFTER the K-loop (only feeds epilogue) - removes a
//     serialized global round-trip at kernel start
//   - same XOR chunk swizzle (0 conflicts measured), XCD swizzle 784=8x98

typedef __attribute__((ext_vector_type(8))) short short8;
typedef __attribute__((ext_vector_type(4))) float floatx4;

typedef __attribute__((address_space(1))) const void* gas_ptr;
typedef __attribute__((address_space(3))) void* las_ptr;

__device__ static inline void gl2lds16(const void* g, void* l) {
    __builtin_amdgcn_global_load_lds((gas_ptr)g, (las_ptr)l, 16, 0, 0);
}

__device__ static inline float bf2f(unsigned short u) {
    union { unsigned int i; float f; } x; x.i = ((unsigned int)u) << 16; return x.f;
}
__device__ static inline unsigned short f2bf(float f) {
    union { float f; unsigned int i; } x; x.f = f;
    unsigned int r = (x.i + 0x7FFFu + ((x.i >> 16) & 1u)) >> 16;  // RNE
    return (unsigned short)r;
}

// Per-wave dtype sniff: low halves of fp32 words are random mantissa bits
// (~19% plausible bf16 exponents); true bf16 data is ~100% plausible.
// Uniform across the wave via ballot; requires all 64 lanes active.
__device__ static inline bool wave_detect_bf16(const unsigned int* __restrict__ p) {
    const int lane = threadIdx.x & 63;
    int cnt = 0;
#pragma unroll
    for (int r = 0; r < 4; ++r) {
        unsigned int w = p[r * 64 + lane];
        unsigned short lo = (unsigned short)(w & 0xFFFFu);
        int e = (lo >> 7) & 0xFF;
        bool plaus = (lo == 0) || (e >= 96 && e <= 144);
        cnt += (int)__popcll(__ballot(plaus));
    }
    return cnt >= 205;   // >=80% of 256 sampled halves
}

// ---------------- weight repack -> [9][256][128] bf16 ----------------------
__global__ void wt_repack(const void* __restrict__ wsrc,
                          unsigned short* __restrict__ wt) {
    const bool isbf = wave_detect_bf16((const unsigned int*)wsrc);
    int idx = blockIdx.x * 256 + threadIdx.x;       // 294912 total, grid=1152
    int ci  = idx & 127;
    int co  = (idx >> 7) & 255;
    int off = idx >> 15;                            // 0..8 = dh*3+dw
    size_t s = (size_t)(co * 128 + ci) * 9 + off;
    float v = isbf ? bf2f(((const unsigned short*)wsrc)[s])
                   : ((const float*)wsrc)[s];
    wt[idx] = f2bf(v);
}

// ------- x NCHW -> padded NHWC bf16 [32][58][58][128], LDS transpose -------
__global__ __launch_bounds__(256) void x_repack(
    const void* __restrict__ xsrc, unsigned short* __restrict__ xp) {
    __shared__ unsigned short tile[56 * 130];   // pad 130: conflict-free
    const int bh  = blockIdx.x;                 // 32*58 blocks
    const int b   = bh / 58, hp = bh - b * 58;  // hp in [0,58)
    const int tid = threadIdx.x;
    unsigned short* row = xp + (size_t)(b * 58 + hp) * 58 * 128;
    if (hp == 0 || hp == 57) {                  // top/bottom pad rows
        uint4 z; z.x = z.y = z.z = z.w = 0u;
        uint4* r = (uint4*)row;
        for (int t = tid; t < 928; t += 256) r[t] = z;
        return;
    }
    const bool isbf = wave_detect_bf16((const unsigned int*)xsrc);
    const int h = hp - 1;
    if (isbf) {
        const unsigned short* xs =
            (const unsigned short*)xsrc + (size_t)b * 128 * 3136 + h * 56;
#pragma unroll
        for (int it = 0; it < 7; ++it) {        // 1792 items = 128ci x 14 w4
            int idx = it * 256 + tid;
            int ci = idx / 14, w4 = idx - ci * 14;
            ushort4 v = *(const ushort4*)(xs + (size_t)ci * 3136 + w4 * 4);
            tile[(w4 * 4 + 0) * 130 + ci] = v.x;
            tile[(w4 * 4 + 1) * 130 + ci] = v.y;
            tile[(w4 * 4 + 2) * 130 + ci] = v.z;
            tile[(w4 * 4 + 3) * 130 + ci] = v.w;
        }
    } else {
        const float* xs = (const float*)xsrc + (size_t)b * 128 * 3136 + h * 56;
#pragma unroll
        for (int it = 0; it < 7; ++it) {
            int idx = it * 256 + tid;
            int ci = idx / 14, w4 = idx - ci * 14;
            float4 v = *(const float4*)(xs + (size_t)ci * 3136 + w4 * 4);
            tile[(w4 * 4 + 0) * 130 + ci] = f2bf(v.x);
            tile[(w4 * 4 + 1) * 130 + ci] = f2bf(v.y);
            tile[(w4 * 4 + 2) * 130 + ci] = f2bf(v.z);
            tile[(w4 * 4 + 3) * 130 + ci] = f2bf(v.w);
        }
    }
    __syncthreads();
#pragma unroll
    for (int it = 0; it < 4; ++it) {
        int k = it * 256 + tid;                 // 928 chunks of 16B
        if (k >= 928) break;
        int wq = k >> 4, cc = k & 15;
        uint4 v;
        if (wq == 0 || wq == 57) { v.x = v.y = v.z = v.w = 0u; }
        else {
            const unsigned short* p = &tile[(wq - 1) * 130 + cc * 8];
            union { unsigned short s[8]; uint4 u; } pk;
#pragma unroll
            for (int j = 0; j < 8; ++j) pk.s[j] = p[j];
            v = pk.u;
        }
        *(uint4*)(row + wq * 128 + cc * 8) = v;
    }
}

// -------- main: 8-wave 64x64-per-wave implicit GEMM, 256x128 tile ----------
// K decomposition: 36 "halves" h = off*4 + q; off=h>>2 (0..8 = dh*3+dw),
// k-range within off = q*32 (q = h&3). Half-buffer (24KB): A[256 cout][32k]
// bf16 at +0 (16KB), B[128 n][32k] bf16 at +16384 (8KB). Rows are 64B; phys
// 16B chunk p of row r holds logical k-chunk p ^ ((r>>1)&3).
__global__ __launch_bounds__(512, 4) void conv_mfma(
    const unsigned short* __restrict__ xp,   // [32][58][58][128] bf16
    const unsigned short* __restrict__ wt,   // [9][256][128] bf16
    const void* __restrict__ bias,           // [256] fp32 or bf16
    void* __restrict__ out,                  // [32][256][56][56] fp32 or bf16
    const void* __restrict__ xorig)          // for dtype sniff only
{
    __shared__ __align__(16) char lds[73728];   // 3 half-buffers x 24KB
    const int tid   = threadIdx.x;
    const int lane  = tid & 63;
    const int wv    = tid >> 6;        // 0..7
    const int bid   = blockIdx.x;
    const int ntile = (bid & 7) * 98 + (bid >> 3);   // XCD swizzle, 784=8x98

    // ---- staging setup (3 x 1KB chunks per wave per half: 2 A + 1 B) -----
    // A half = 16 chunks (256 cout rows), B half = 8 chunks (128 n rows).
    // Wave wv stages A chunks wv*2+s (s=0..1) and B chunk wv. Chunk c covers
    // LDS rows [c*16, c*16+16); lane writes row c*16 + (lane>>2), phys 16B
    // slot lane&3 holding logical k-chunk clg = (lane&3)^((lane>>3)&3)
    // -> LDS dest = chunkbase + lane*16 (linear, as gl2lds16 requires).
    const int clg  = (lane & 3) ^ ((lane >> 3) & 3);
    const int rsub = lane >> 2;
    unsigned sbA[2], sbB;
    int dbA[2], dbB;
#pragma unroll
    for (int s = 0; s < 2; ++s) {
        const int c  = wv * 2 + s;
        const int co = c * 16 + rsub;
        sbA[s] = (unsigned)(co * 256 + clg * 16);          // byte into wt
        dbA[s] = c * 1024;
    }
    {
        const int n = ntile * 128 + wv * 16 + rsub;
        const int b = n / 3136, rem = n - b * 3136;
        const int hh = rem / 56, ww = rem - hh * 56;
        sbB = (unsigned)(((b * 58 + hh) * 58 + ww) * 256 + clg * 16);
        dbB = 16384 + wv * 1024;
    }

    // ---- fragment read setup ----------------------------------------------
    const int fr = lane & 15;
    const int ph = (lane >> 4) ^ ((fr >> 1) & 3);
    const int wm2 = wv >> 1;           // 0..3  (M: 64 couts per wave)
    const int wn2 = wv & 1;            // 0..1  (N: 64 cols per wave)
    const int aOff = (wm2 * 64 + fr) * 64 + ph * 16;          // + i*1024
    const int bOff = 16384 + (wn2 * 64 + fr) * 64 + ph * 16;  // + j*1024

    floatx4 acc[4][4] = {};

    // ---- prologue: stage halves 0,1 (off=0 -> dA=dB=q*64) -----------------
#pragma unroll
    for (int h = 0; h < 2; ++h) {
        char* lb = lds + h * 24576;
        const int d = h * 64;
        gl2lds16((const char*)wt + sbA[0] + d, lb + dbA[0]);
        gl2lds16((const char*)wt + sbA[1] + d, lb + dbA[1]);
        gl2lds16((const char*)xp + sbB + d, lb + dbB);
    }
    __builtin_amdgcn_s_waitcnt(0x3F73);   // vmcnt(3): half 0 landed
    __builtin_amdgcn_s_barrier();

    // ---- main loop: 36 halves ---------------------------------------------
    int bf_ = 0, st_ = 2;                 // h%3, (h+2)%3
#pragma unroll 3
    for (int h = 0; h < 36; ++h) {
        const char* la = lds + bf_ * 24576;
        // stage h+2 into buf (h+2)%3 (read at h-1, retired at h-1's barrier)
        if (h < 34) {
            char* sd = lds + st_ * 24576;
            const int hn  = h + 2;
            const int off = hn >> 2, q = hn & 3;
            const int dA  = off * 65536 + q * 64;
            const int dh_ = off / 3, dw_ = off - dh_ * 3;
            const int dB  = (dh_ * 58 + dw_) * 256 + q * 64;
            gl2lds16((const char*)wt + sbA[0] + dA, sd + dbA[0]);
            gl2lds16((const char*)wt + sbA[1] + dA, sd + dbA[1]);
            gl2lds16((const char*)xp + sbB + dB, sd + dbB);
        }
        short8 af[4], bf[4];
#pragma unroll
        for (int i = 0; i < 4; ++i)
            af[i] = *(const short8*)(la + aOff + i * 1024);
#pragma unroll
        for (int j = 0; j < 4; ++j)
            bf[j] = *(const short8*)(la + bOff + j * 1024);
        __builtin_amdgcn_s_setprio(1);
#pragma unroll
        for (int i = 0; i < 4; ++i)
#pragma unroll
            for (int j = 0; j < 4; ++j)
                acc[i][j] = __builtin_amdgcn_mfma_f32_16x16x32_bf16(
                    af[i], bf[j], acc[i][j], 0, 0, 0);
        __builtin_amdgcn_s_setprio(0);
        // counted gate: h+1 resident before next iteration's reads; h+2's
        // 3 loads (this wave's) stay in flight across the barrier.
        if (h < 34) {
            __builtin_amdgcn_s_waitcnt(0x3F73);   // vmcnt(3)
            __builtin_amdgcn_s_barrier();
        } else if (h == 34) {
            __builtin_amdgcn_s_waitcnt(0x3F70);   // vmcnt(0): h35 landed
            __builtin_amdgcn_s_barrier();
        }
        bf_ = (bf_ == 2) ? 0 : bf_ + 1;
        st_ = (st_ == 2) ? 0 : st_ + 1;
    }

    // ---- dtype sniff (feeds only the epilogue; off the startup path) ------
    const bool isbf = wave_detect_bf16((const unsigned int*)xorig);

    // ---- epilogue: D[row=cout(quad*4+reg)][col=spatial(lane&15)] ----------
    const int q4 = (lane >> 4) << 2;
    int nb[4], ns[4];
#pragma unroll
    for (int j = 0; j < 4; ++j) {
        const int n = ntile * 128 + wn2 * 64 + j * 16 + fr;
        nb[j] = n / 3136;
        ns[j] = n - nb[j] * 3136;
    }
#pragma unroll
    for (int i = 0; i < 4; ++i) {
        const int co = wm2 * 64 + i * 16 + q4;
        float bv[4];
        if (isbf) {
            const ushort4 bb = *(const ushort4*)((const unsigned short*)bias + co);
            bv[0] = bf2f(bb.x); bv[1] = bf2f(bb.y);
            bv[2] = bf2f(bb.z); bv[3] = bf2f(bb.w);
        } else {
            const float4 bb = *(const float4*)((const float*)bias + co);
            bv[0] = bb.x; bv[1] = bb.y; bv[2] = bb.z; bv[3] = bb.w;
        }
#pragma unroll
        for (int j = 0; j < 4; ++j) {
#pragma unroll
            for (int r = 0; r < 4; ++r) {
                const float v = acc[i][j][r] + bv[r];
                const size_t o = (size_t)nb[j] * 802816 +
                                 (size_t)(co + r) * 3136 + ns[j];
                if (isbf) ((unsigned short*)out)[o] = f2bf(v);
                else      ((float*)out)[o] = v;
            }
        }
    }
}

// ---------------- fallback: naive direct conv fp32 (if ws too small) -------
__global__ void conv_naive(const float* __restrict__ x,
                           const float* __restrict__ w,
                           const float* __restrict__ bias,
                           float* __restrict__ out) {
    long long i = (long long)blockIdx.x * 256 + threadIdx.x;
    if (i >= 25690112LL) return;
    int wo = (int)(i % 56); long long t = i / 56;
    int ho = (int)(t % 56); t /= 56;
    int co = (int)(t % 256); int b = (int)(t / 256);
    float acc = bias[co];
    for (int ci = 0; ci < 128; ++ci)
        for (int dh = 0; dh < 3; ++dh) {
            int hi = ho + dh - 1; if ((unsigned)hi >= 56u) continue;
            for (int dw = 0; dw < 3; ++dw) {
                int wi = wo + dw - 1; if ((unsigned)wi >= 56u) continue;
                acc += x[((size_t)(b * 128 + ci) * 56 + hi) * 56 + wi] *
                       w[((co * 128 + ci) * 3 + dh) * 3 + dw];
            }
        }
    out[i] = acc;
}

extern "C" void kernel_launch(void* const* d_in, const int* in_sizes, int n_in,
                              void* d_out, int out_size, void* d_ws, size_t ws_size,
                              hipStream_t stream) {
    const void* x    = d_in[0];
    const void* w    = d_in[1];
    const void* bias = d_in[2];
    // d_in[3] = approximate (scalar, does not affect exact math) — unused.

    const size_t xp_bytes = (size_t)32 * 58 * 58 * 128 * 2;   // 27,557,888
    const size_t wt_off   = xp_bytes;
    const size_t wt_bytes = (size_t)9 * 256 * 128 * 2;        // 589,824
    const size_t need     = wt_off + wt_bytes;

    if (ws_size >= need) {
        unsigned short* xp = (unsigned short*)d_ws;
        unsigned short* wt = (unsigned short*)((char*)d_ws + wt_off);
        x_repack<<<32 * 58, 256, 0, stream>>>(x, xp);
        wt_repack<<<1152, 256, 0, stream>>>(w, wt);
        conv_mfma<<<dim3(784, 1, 1), 512, 0, stream>>>(xp, wt, bias, d_out, x);
    } else {
        conv_naive<<<(25690112 + 255) / 256, 256, 0, stream>>>(
            (const float*)x, (const float*)w, (const float*)bias, (float*)d_out);
    }
}